// Round 7
// baseline (35.411 us; speedup 1.0000x reference)
//
#include <hip/hip_runtime.h>

// Problem constants (from reference setup_inputs)
#define NUM_VARS  256
#define NUM_NODES 65536
#define NUM_CATS  256
#define BATCH     512
#define NODES_PER_BLOCK 16

typedef __attribute__((ext_vector_type(4))) float f32x4;
typedef __attribute__((ext_vector_type(4))) int   i32x4;

// out[node*BATCH + b] = log(params[s_pids[node] + data[vids[node]*BATCH + b]])
//
// r6 structure (35.1us) with 2x nodes/block to amortize the vmcnt(0)+barrier:
//  - Phase 1: global_load_lds (width 16) DMAs 16 raw 1KiB param rows to LDS
//    (wave w stages rows w, w+4, w+8, w+12). No VGPR round-trip.
//  - All 8 data int4 loads per thread issued while the DMA is in flight.
//  - ONE __syncthreads per block (4096 total, half of r6) drains everything.
//  - Phase 2: LDS gather, log on gathered value, NT-stream f32x4 out.
__global__ __launch_bounds__(256) void input_layer_kernel(
    const int*   __restrict__ data,    // [NUM_VARS * BATCH] int32
    const float* __restrict__ params,  // [NUM_NODES * NUM_CATS]
    const int*   __restrict__ vids,    // [NUM_NODES]
    const int*   __restrict__ s_pids,  // [NUM_NODES]
    float*       __restrict__ out)     // [NUM_NODES * BATCH] fp32
{
    __shared__ float praw[NODES_PER_BLOCK * NUM_CATS];   // 16 KiB raw params
    const int t    = threadIdx.x;
    const int w    = t >> 6;                             // wave 0..3
    const int lane = t & 63;
    const int gb   = blockIdx.x * NODES_PER_BLOCK;

    // ---- Phase 1: async DMA param rows -> LDS (wave w: rows w+4h) ----
#pragma unroll
    for (int h = 0; h < 4; ++h) {
        const int r    = w + h * 4;                      // node-local row 0..15
        const int spid = s_pids[gb + r];                 // uniform addr -> broadcast
        const float* src = &params[spid + lane * 4];     // per-lane global addr
        __builtin_amdgcn_global_load_lds(
            (const __attribute__((address_space(1))) unsigned int*)src,
            (__attribute__((address_space(3))) unsigned int*)&praw[r * NUM_CATS],
            16, 0, 0);                                   // lane l -> base + 16*l
    }

    // ---- Overlap: issue all data loads while DMA is in flight ----
    int   k[8], bb[8];
    i32x4 dv[8];
#pragma unroll
    for (int ch = 0; ch < 8; ++ch) {
        const int e = ch * 1024 + t * 4;                 // element in 16x512 group
        k[ch]  = e >> 9;                                 // node-local 0..15
        bb[ch] = e & (BATCH - 1);
        const int vid = vids[gb + k[ch]];                // uniform -> broadcast
        dv[ch] = *reinterpret_cast<const i32x4*>(&data[vid * BATCH + bb[ch]]);
    }

    __syncthreads();   // one vmcnt(0)+barrier per block: DMA + data done

    // ---- Phase 2: LDS gather, log, NT stream out ----
#pragma unroll
    for (int ch = 0; ch < 8; ++ch) {
        const float* const row = &praw[k[ch] * NUM_CATS];
        f32x4 r;
        r.x = __logf(row[dv[ch].x]);
        r.y = __logf(row[dv[ch].y]);
        r.z = __logf(row[dv[ch].z]);
        r.w = __logf(row[dv[ch].w]);
        __builtin_nontemporal_store(r, reinterpret_cast<f32x4*>(
            &out[(gb + k[ch]) * BATCH + bb[ch]]));
    }
}

extern "C" void kernel_launch(void* const* d_in, const int* in_sizes, int n_in,
                              void* d_out, int out_size, void* d_ws, size_t ws_size,
                              hipStream_t stream) {
    const int*   data   = (const int*)d_in[0];
    const float* params = (const float*)d_in[1];
    const int*   vids   = (const int*)d_in[2];
    const int*   s_pids = (const int*)d_in[3];
    float*       out    = (float*)d_out;

    const int block = 256;
    const int grid  = NUM_NODES / NODES_PER_BLOCK;       // 4096 blocks, no tail
    input_layer_kernel<<<grid, block, 0, stream>>>(data, params, vids, s_pids, out);
}